// Round 12
// baseline (1618.847 us; speedup 1.0000x reference)
//
#include <hip/hip_runtime.h>

typedef unsigned short u16;
typedef __attribute__((ext_vector_type(4))) float f32x4;
typedef __attribute__((ext_vector_type(8))) __bf16 bf16x8;

#define SEQ   4096
#define HID   4096
#define HID3  12288

__device__ __forceinline__ float bf2f(u16 u){
  union { unsigned int i; float f; } v; v.i = ((unsigned int)u) << 16; return v.f;
}
__device__ __forceinline__ u16 f2bf(float f){
  union { float f; unsigned int i; } v; v.f = f;
  unsigned int r = (v.i + 0x7FFFu + ((v.i >> 16) & 1u)) >> 16;
  return (u16)r;
}
__device__ __forceinline__ float slope_of(int h){
  const float factor = 1.0f - 1.0f/(31.0f + 1e-5f) + 1e-5f;
  return exp2f(-0.25f * (float)(h + 1)) * factor;
}
__device__ __forceinline__ bf16x8 ld_bf8(const u16* p){
  return __builtin_bit_cast(bf16x8, *(const uint4*)p);
}
__device__ __forceinline__ void gload_lds16(const u16* g, u16* l){
  __builtin_amdgcn_global_load_lds((const __attribute__((address_space(1))) void*)g,
                                   (__attribute__((address_space(3))) void*)l, 16, 0, 0);
}

// ---------------- fused fp32 -> bf16 convert of all 4 arrays (1 launch) ----------------
#define CVT_B0 33554432L
#define CVT_B1 83886080L
#define CVT_B2 100663296L
#define CVT_B3 117440512L
__global__ __launch_bounds__(256) void cvt4_kernel(const float* __restrict__ s0,
                                                   const float* __restrict__ s1,
                                                   const float* __restrict__ s2,
                                                   const float* __restrict__ s3,
                                                   u16* __restrict__ dst){
  long i = ((long)blockIdx.x * 256 + threadIdx.x) * 4;
  long stride = (long)gridDim.x * 1024;
  for (; i < CVT_B3; i += stride){
    const float* src;
    long off;
    if (i < CVT_B0){ src = s0; off = i; }
    else if (i < CVT_B1){ src = s1; off = i - CVT_B0; }
    else if (i < CVT_B2){ src = s2; off = i - CVT_B1; }
    else { src = s3; off = i - CVT_B2; }
    float4 v = *(const float4*)(src + off);
    ushort4 o;
    o.x = f2bf(v.x); o.y = f2bf(v.y); o.z = f2bf(v.z); o.w = f2bf(v.w);
    *(ushort4*)(dst + i) = o;
  }
}

// ============ 256x256 tile, BK=64, 5-slot-ring, 1-barrier/period bf16 GEMM ============
// ROUND-9 K-LOOP VERBATIM (verified best: 736us, MfmaUtil 54%, 0 bank conflicts).
// R12 change (outside K-loop): bm-FAST block order within each XCD's contiguous
// bswz chunk -> per bn the 2MB B-panel is L2-resident and A streams once (L3-holds
// both A 67MB and B 100MB).  Old bn-fast order re-streamed B 16x -> FETCH 1.8GB.
// EPI: 0 = silu->bf16 ; 1 = sigmoid(x)*Aux*Rs[row]*Nw[col] -> bf16 ; 2 = raw->fp32.
template<int EPI>
__global__ __launch_bounds__(512) void gemm256(
    const u16* __restrict__ A, const u16* __restrict__ B, void* __restrict__ C,
    const u16* __restrict__ Aux, const float* __restrict__ Rs,
    const float* __restrict__ Nw, int M, int N, int K)
{
  __shared__ u16 ring[5][16384];
  const int t = threadIdx.x;
  const int w = t >> 6, l = t & 63, lr = l & 15, lk = l >> 4;
  const int mw = w >> 2, nw = w & 3;
  const int nbm = M >> 8;
  int nwg = gridDim.x;
  int bid = blockIdx.x;
  int bswz = (bid & 7) * (nwg >> 3) + (bid >> 3);
  int bm = bswz % nbm, bn = bswz / nbm;     // bm-fast: B-panel L2-resident per bn
  const u16* Abase = A + (long)(bm * 256) * K;
  const u16* Bbase = B + (long)(bn * 256) * K;
  const int NT = K >> 6;

  // staging decode: issue i covers LDS bytes [i*8192 + t*16, +16)
  int sr[2], sku[2];
#pragma unroll
  for (int i = 0; i < 2; ++i){
    int dr = i * 64 + (t >> 3);
    int ul = (t & 7) ^ (dr & 7);
    sr[i]  = 2 * dr + (ul >> 2);
    sku[i] = ul & 3;
  }
  // frag read offsets (u16 units within a 16KB chunk)
  int offA[8], offB[4];
#pragma unroll
  for (int fn = 0; fn < 8; ++fn){
    int row = mw * 128 + fn * 16 + lr;
    offA[fn] = (row >> 1) * 64 + (((((row & 1) << 2) + lk) ^ ((row >> 1) & 7)) << 3);
  }
#pragma unroll
  for (int fe = 0; fe < 4; ++fe){
    int row = nw * 64 + fe * 16 + lr;
    offB[fe] = (row >> 1) * 64 + (((((row & 1) << 2) + lk) ^ ((row >> 1) & 7)) << 3);
  }

  auto stageA = [&](int kt, int c, int slot, int i){
    gload_lds16(Abase + (long)sr[i] * K + kt * 64 + c * 32 + sku[i] * 8,
                &ring[slot][i * 4096 + w * 512]);
  };
  auto stageB = [&](int kt, int c, int slot, int i){
    gload_lds16(Bbase + (long)sr[i] * K + kt * 64 + c * 32 + sku[i] * 8,
                &ring[slot][8192 + i * 4096 + w * 512]);
  };

  f32x4 acc[8][4] = {};

  // prologue: (0,0)->slot0, (0,1)->slot1, (1,0)->slot2
  stageA(0,0,0,0); stageA(0,0,0,1); stageB(0,0,0,0); stageB(0,0,0,1);
  stageA(0,1,1,0); stageA(0,1,1,1); stageB(0,1,1,0); stageB(0,1,1,1);
  if (1 < NT){ stageA(1,0,2,0); stageA(1,0,2,1); stageB(1,0,2,0); stageB(1,0,2,1); }
  asm volatile("s_waitcnt vmcnt(4)" ::: "memory");
  __builtin_amdgcn_s_barrier();

  int sa = 0;
  for (int p = 0; p < NT; ++p){
    int sb = sa + 1; if (sb >= 5) sb -= 5;
    int sx = sa + 3; if (sx >= 5) sx -= 5;   // chunk (p+1,1)
    int sy = sa + 4; if (sy >= 5) sy -= 5;   // chunk (p+2,0)
    const u16* Aa = &ring[sa][0];
    const u16* Ab = &ring[sb][0];
    const u16* Ba = &ring[sa][8192];
    const u16* Bb = &ring[sb][8192];
    bf16x8 bh0[4], bh1[4], afc0[8], afc1[8];

    // ---- phase 1: chunk sa, fn0-3 ----
#pragma unroll
    for (int fe = 0; fe < 4; ++fe) bh0[fe] = ld_bf8(Ba + offB[fe]);
#pragma unroll
    for (int fn = 0; fn < 4; ++fn) afc0[fn] = ld_bf8(Aa + offA[fn]);
#pragma unroll
    for (int fn = 4; fn < 8; ++fn) afc0[fn] = ld_bf8(Aa + offA[fn]);
    if (p + 1 < NT){ stageA(p+1, 1, sx, 0); stageA(p+1, 1, sx, 1); }
    asm volatile("s_waitcnt lgkmcnt(4)" ::: "memory");   // bh0 + afc0[0..3] ready
    __builtin_amdgcn_sched_barrier(0);
    __builtin_amdgcn_s_setprio(1);
#pragma unroll
    for (int fn = 0; fn < 4; ++fn)
#pragma unroll
      for (int fe = 0; fe < 4; ++fe)
        acc[fn][fe] = __builtin_amdgcn_mfma_f32_16x16x32_bf16(afc0[fn], bh0[fe], acc[fn][fe], 0, 0, 0);
    __builtin_amdgcn_s_setprio(0);

    // ---- phase 2: chunk sa, fn4-7 ----
#pragma unroll
    for (int fe = 0; fe < 4; ++fe) bh1[fe] = ld_bf8(Bb + offB[fe]);
#pragma unroll
    for (int fn = 0; fn < 4; ++fn) afc1[fn] = ld_bf8(Ab + offA[fn]);
    if (p + 1 < NT){ stageB(p+1, 1, sx, 0); stageB(p+1, 1, sx, 1); }
    asm volatile("s_waitcnt lgkmcnt(8)" ::: "memory");   // afc0[4..7] ready
    __builtin_amdgcn_sched_barrier(0);
    __builtin_amdgcn_s_setprio(1);
#pragma unroll
    for (int fn = 4; fn < 8; ++fn)
#pragma unroll
      for (int fe = 0; fe < 4; ++fe)
        acc[fn][fe] = __builtin_amdgcn_mfma_f32_16x16x32_bf16(afc0[fn], bh0[fe], acc[fn][fe], 0, 0, 0);
    __builtin_amdgcn_s_setprio(0);

    // ---- phase 3: chunk sb, fn0-3 ----
#pragma unroll
    for (int fn = 4; fn < 8; ++fn) afc1[fn] = ld_bf8(Ab + offA[fn]);
    if (p + 2 < NT){ stageA(p+2, 0, sy, 0); stageA(p+2, 0, sy, 1); }
    asm volatile("s_waitcnt lgkmcnt(4)" ::: "memory");   // bh1 + afc1[0..3] ready
    __builtin_amdgcn_sched_barrier(0);
    __builtin_amdgcn_s_setprio(1);
#pragma unroll
    for (int fn = 0; fn < 4; ++fn)
#pragma unroll
      for (int fe = 0; fe < 4; ++fe)
        acc[fn][fe] = __builtin_amdgcn_mfma_f32_16x16x32_bf16(afc1[fn], bh1[fe], acc[fn][fe], 0, 0, 0);
    __builtin_amdgcn_s_setprio(0);

    // ---- phase 4: chunk sb, fn4-7 ----
    if (p + 2 < NT){ stageB(p+2, 0, sy, 0); stageB(p+2, 0, sy, 1); }
    asm volatile("s_waitcnt lgkmcnt(0)" ::: "memory");   // afc1[4..7] ready
    __builtin_amdgcn_sched_barrier(0);
    __builtin_amdgcn_s_setprio(1);
#pragma unroll
    for (int fn = 4; fn < 8; ++fn)
#pragma unroll
      for (int fe = 0; fe < 4; ++fe)
        acc[fn][fe] = __builtin_amdgcn_mfma_f32_16x16x32_bf16(afc1[fn], bh1[fe], acc[fn][fe], 0, 0, 0);
    __builtin_amdgcn_s_setprio(0);

    // ---- single boundary sync per period ----
    if (p + 2 < NT) asm volatile("s_waitcnt vmcnt(4)" ::: "memory");
    else            asm volatile("s_waitcnt vmcnt(0)" ::: "memory");
    __builtin_amdgcn_s_barrier();
    sa += 2; if (sa >= 5) sa -= 5;
  }

  long crow = (long)bm * 256 + mw * 128 + lk * 4;
  long ccol = (long)bn * 256 + nw * 64 + lr;
#pragma unroll
  for (int fn = 0; fn < 8; ++fn)
#pragma unroll
    for (int fe = 0; fe < 4; ++fe)
#pragma unroll
      for (int reg = 0; reg < 4; ++reg){
        long row = crow + fn * 16 + reg;
        long col = ccol + fe * 16;
        float x = acc[fn][fe][reg];
        if (EPI == 0){
          ((u16*)C)[row * N + col] = f2bf(x / (1.0f + __expf(-x)));
        } else if (EPI == 1){
          float g = 1.0f / (1.0f + __expf(-x));
          float a = bf2f(Aux[row * N + col]);
          ((u16*)C)[row * N + col] = f2bf(g * a * Rs[row] * Nw[col]);
        } else {
          ((float*)C)[row * N + col] = x;
        }
      }
}

// ------- attention phase 1 (MFMA): ct[e][d] = sum_n v[n][e] * k[n][d] * kdec[n] -------
__global__ __launch_bounds__(256) void attn_contrib(
    const u16* __restrict__ qkv, float* __restrict__ ct)
{
  __shared__ u16 VT[128 * 258];
  __shared__ u16 KT[128 * 258];
  int wg = blockIdx.x;
  int bh = wg >> 4, blk = wg & 15;
  int b = bh >> 5, h = bh & 31;
  int t = threadIdx.x;
  float slope = slope_of(h);
  const u16* kg = qkv + ((long)(b * SEQ + blk * 256)) * HID3 + h * 384 + 128;
  const u16* vg = kg + 128;
#pragma unroll
  for (int i = 0; i < 16; ++i){
    int chunk = t + i * 256;
    int row = chunk >> 4, c8 = (chunk & 15) << 3;
    float kd = __expf(-slope * (float)(255 - row));
    uint4 kk = *(const uint4*)&kg[(long)row * HID3 + c8];
    uint4 vv = *(const uint4*)&vg[(long)row * HID3 + c8];
    const u16* ks = (const u16*)&kk;
    const u16* vs = (const u16*)&vv;
#pragma unroll
    for (int x = 0; x < 8; ++x){
      KT[(c8 + x) * 258 + row] = f2bf(bf2f(ks[x]) * kd);
      VT[(c8 + x) * 258 + row] = vs[x];
    }
  }
  __syncthreads();
  int w = t >> 6, l = t & 63, lr = l & 15, lk = l >> 4;
  int we = (w >> 1) * 64, wd = (w & 1) * 64;
  f32x4 acc[4][4] = {};
  for (int nc = 0; nc < 8; ++nc){
    bf16x8 va[4], kb[4];
#pragma unroll
    for (int f = 0; f < 4; ++f) va[f] = ld_bf8(&VT[(we + f * 16 + lr) * 258 + nc * 32 + lk * 8]);
#pragma unroll
    for (int f = 0; f < 4; ++f) kb[f] = ld_bf8(&KT[(wd + f * 16 + lr) * 258 + nc * 32 + lk * 8]);
#pragma unroll
    for (int fe = 0; fe < 4; ++fe)
#pragma unroll
      for (int fd = 0; fd < 4; ++fd)
        acc[fe][fd] = __builtin_amdgcn_mfma_f32_16x16x32_bf16(va[fe], kb[fd], acc[fe][fd], 0, 0, 0);
  }
  float* out = ct + (long)wg * 16384;
#pragma unroll
  for (int fe = 0; fe < 4; ++fe)
#pragma unroll
    for (int fd = 0; fd < 4; ++fd)
#pragma unroll
      for (int reg = 0; reg < 4; ++reg){
        int e = we + fe * 16 + lk * 4 + reg;
        int d = wd + fd * 16 + lr;
        out[e * 128 + d] = acc[fe][fd][reg];
      }
}

// ---------------- attention phase 2: decayed prefix scan (d-sliced, 256 blocks) ----
__global__ __launch_bounds__(256) void attn_scan(const float* __restrict__ ct,
                                                 u16* __restrict__ stTb)
{
  int g = blockIdx.x;
  int bh = g >> 2, sl = g & 3;
  int t = threadIdx.x;
  float bdec = __expf(-slope_of(bh & 31) * 256.0f);
  float cur[16];
#pragma unroll
  for (int i = 0; i < 16; ++i) cur[i] = 0.f;
  const float* base = ct + (long)bh * 16 * 16384 + sl * 4096;
  u16* ob = stTb + (long)bh * 16 * 16384 + sl * 4096;
  for (int blkI = 0; blkI < 16; ++blkI){
    const float* p = base + (long)blkI * 16384;
    u16* o = ob + (long)blkI * 16384;
#pragma unroll
    for (int i = 0; i < 16; ++i){
      o[t + i * 256] = f2bf(cur[i]);
      cur[i] = cur[i] * bdec + p[t + i * 256];
    }
  }
}

// ---------------- attention phase 3 (MFMA): intra + inter + fused RMS partials ----
__global__ __launch_bounds__(512) void attn_mfma(
    const u16* __restrict__ qkv, const u16* __restrict__ stTb, u16* __restrict__ attn,
    float* __restrict__ pss)
{
  __shared__ u16 Ks[256 * 130];
  __shared__ u16 VTs[128 * 258];
  __shared__ u16 Ps[4][64 * 34];
  int wg = blockIdx.x;
  int bh = wg >> 4, blk = wg & 15;
  int b = bh >> 5, h = bh & 31;
  int t = threadIdx.x;
  int w = t >> 6, l = t & 63, lr = l & 15, lk = l >> 4;
  int r = w >> 1, c = w & 1;
  float slope = slope_of(h);
  const u16* qg = qkv + ((long)(b * SEQ + blk * 256)) * HID3 + h * 384;
  const u16* kg = qg + 128;
  const u16* vg = qg + 256;

#pragma unroll
  for (int i = 0; i < 8; ++i){
    int chunk = t + i * 512;
    int row = chunk >> 4, c8 = (chunk & 15) << 3;
    *(uint4*)&Ks[row * 130 + c8] = *(const uint4*)&kg[(long)row * HID3 + c8];
    uint4 vv = *(const uint4*)&vg[(long)row * HID3 + c8];
    const u16* vs = (const u16*)&vv;
#pragma unroll
    for (int x = 0; x < 8; ++x) VTs[(c8 + x) * 258 + row] = vs[x];
  }
  bf16x8 qa[4][4];
#pragma unroll
  for (int fn = 0; fn < 4; ++fn)
#pragma unroll
    for (int kc = 0; kc < 4; ++kc)
      qa[fn][kc] = ld_bf8(&qg[(long)(r * 64 + fn * 16 + lr) * HID3 + kc * 32 + lk * 8]);
  f32x4 acc[4][4] = {};
  __syncthreads();

  int mtmax = 2 * r + 1;
  for (int mt = 0; mt < 8; ++mt){
    if (mt <= mtmax){
      f32x4 S[4] = {};
      int mrow = mt * 32 + c * 16 + lr;
      bf16x8 kb[4];
#pragma unroll
      for (int kc = 0; kc < 4; ++kc)
        kb[kc] = ld_bf8(&Ks[mrow * 130 + kc * 32 + lk * 8]);
#pragma unroll
      for (int fn = 0; fn < 4; ++fn)
#pragma unroll
        for (int kc = 0; kc < 4; ++kc)
          S[fn] = __builtin_amdgcn_mfma_f32_16x16x32_bf16(qa[fn][kc], kb[kc], S[fn], 0, 0, 0);
      int m = mt * 32 + c * 16 + lr;
#pragma unroll
      for (int fn = 0; fn < 4; ++fn)
#pragma unroll
        for (int reg = 0; reg < 4; ++reg){
          int n = r * 64 + fn * 16 + lk * 4 + reg;
          float dv = (n >= m) ? __expf(-slope * (float)(n - m)) : 0.f;
          Ps[r][(fn * 16 + lk * 4 + reg) * 34 + c * 16 + lr] = f2bf(S[fn][reg] * dv);
        }
    }
    __syncthreads();
    if (mt <= mtmax){
      bf16x8 pa[4], vb[4];
#pragma unroll
      for (int fn = 0; fn < 4; ++fn)
        pa[fn] = ld_bf8(&Ps[r][(fn * 16 + lr) * 34 + lk * 8]);
#pragma unroll
      for (int fe = 0; fe < 4; ++fe)
        vb[fe] = ld_bf8(&VTs[(c * 64 + fe * 16 + lr) * 258 + mt * 32 + lk * 8]);
#pragma unroll
      for (int fn = 0; fn < 4; ++fn)
#pragma unroll
        for (int fe = 0; fe < 4; ++fe)
          acc[fn][fe] = __builtin_amdgcn_mfma_f32_16x16x32_bf16(pa[fn], vb[fe], acc[fn][fe], 0, 0, 0);
    }
    __syncthreads();
  }

#pragma unroll
  for (int fn = 0; fn < 4; ++fn){
    int n = r * 64 + fn * 16 + lr;
    float qd = __expf(-slope * (float)(n + 1));
#pragma unroll
    for (int kc = 0; kc < 4; ++kc){
      union { bf16x8 v; u16 u[8]; } uu; uu.v = qa[fn][kc];
#pragma unroll
      for (int x = 0; x < 8; ++x) uu.u[x] = f2bf(bf2f(uu.u[x]) * qd);
      qa[fn][kc] = uu.v;
    }
  }
  const u16* sg = stTb + (long)(bh * 16 + blk) * 16384;
#pragma unroll
  for (int kc = 0; kc < 4; ++kc){
    bf16x8 sb2[4];
#pragma unroll
    for (int fe = 0; fe < 4; ++fe)
      sb2[fe] = ld_bf8(&sg[(c * 64 + fe * 16 + lr) * 128 + kc * 32 + lk * 8]);
#pragma unroll
    for (int fn = 0; fn < 4; ++fn)
#pragma unroll
      for (int fe = 0; fe < 4; ++fe)
        acc[fn][fe] = __builtin_amdgcn_mfma_f32_16x16x32_bf16(qa[fn][kc], sb2[fe], acc[fn][fe], 0, 0, 0);
  }

  // write attn + fused RMS partial sums (per row, this wave's 64-col half)
  u16* arow = attn + ((long)(b * SEQ + blk * 256)) * HID + h * 128;
  long rowbase = (long)(b * SEQ + blk * 256 + r * 64);
#pragma unroll
  for (int fn = 0; fn < 4; ++fn)
#pragma unroll
    for (int reg = 0; reg < 4; ++reg){
      float ss = 0.f;
#pragma unroll
      for (int fe = 0; fe < 4; ++fe){
        int n = r * 64 + fn * 16 + lk * 4 + reg;
        int col = c * 64 + fe * 16 + lr;
        float x = acc[fn][fe][reg];
        arow[(long)n * HID + col] = f2bf(x);
        ss += x * x;
      }
      ss += __shfl_xor(ss, 1);
      ss += __shfl_xor(ss, 2);
      ss += __shfl_xor(ss, 4);
      ss += __shfl_xor(ss, 8);
      if (lr == 0){
        int nloc = fn * 16 + lk * 4 + reg;
        pss[(rowbase + nloc) * 64 + h * 2 + c] = ss;
      }
    }
}

// ---------------- RMS finalize: rs[row] = rsqrt(mean(sum partials)+eps) ----------
__global__ __launch_bounds__(256) void rms_finalize(const float* __restrict__ pss,
                                                    float* __restrict__ rs)
{
  int row = blockIdx.x * 256 + threadIdx.x;
  const float* p = pss + (long)row * 64;
  float s = 0.f;
#pragma unroll
  for (int i = 0; i < 64; i += 4){
    float4 v = *(const float4*)(p + i);
    s += v.x + v.y + v.z + v.w;
  }
  rs[row] = rsqrtf(s * (1.0f / 4096.0f) + 1e-5f);
}

// ---------------- launch ----------------
extern "C" void kernel_launch(void* const* d_in, const int* in_sizes, int n_in,
                              void* d_out, int out_size, void* d_ws, size_t ws_size,
                              hipStream_t stream)
{
  const float* hidden = (const float*)d_in[0];
  const float* qkv_w  = (const float*)d_in[1];
  const float* out_w  = (const float*)d_in[2];
  const float* gate_w = (const float*)d_in[3];
  const float* norm_w = (const float*)d_in[4];
  char* ws = (char*)d_ws;
  const long SZ_X  = 67108864L;    // 8192*4096 bf16
  const long SZ_WQ = 100663296L;   // 12288*4096 bf16
  const long SZ_WG = 33554432L;
  const long SZ_WO = 33554432L;
  const long SZ_QA = 201326592L;   // 8192*12288 bf16
  const long SZ_AT = 67108864L;    // 8192*4096 bf16
  u16* Xb   = (u16*)(ws);
  u16* Wq   = (u16*)(ws + SZ_X);
  u16* Wg   = (u16*)(ws + SZ_X + SZ_WQ);
  u16* Wo   = (u16*)(ws + SZ_X + SZ_WQ + SZ_WG);
  u16* qact = (u16*)(ws + SZ_X + SZ_WQ + SZ_WG + SZ_WO);
  u16* attn = (u16*)(ws + SZ_X + SZ_WQ + SZ_WG + SZ_WO + SZ_QA);
  float* st   = (float*)Wq;        // 67MB, overlays Wq (dead after gemm<0>)
  u16*   stTb = (u16*)(ws + SZ_X + 67108864L);
  float* pss   = (float*)Wq;                         // 2MB, overlays st (dead after scan)
  float* rsbuf = (float*)(ws + SZ_X + 4194304L);     // 32KB, same dead region
  u16* gated = qact;               // overlays qkv activations (dead after attention)
  if (ws_size < (size_t)(SZ_X + SZ_WQ + SZ_WG + SZ_WO + SZ_QA + SZ_AT)) return;

  // one fused conversion pass: Xb | Wq | Wg | Wo
  cvt4_kernel<<<2048, 256, 0, stream>>>(hidden, qkv_w, gate_w, out_w, Xb);

  gemm256<0><<<32 * 48, 512, 0, stream>>>(Xb, Wq, (void*)qact, nullptr, nullptr, nullptr,
                                          8192, 12288, 4096);

  attn_contrib<<<1024, 256, 0, stream>>>(qact, st);
  attn_scan<<<256, 256, 0, stream>>>(st, stTb);
  attn_mfma<<<1024, 512, 0, stream>>>(qact, stTb, attn, pss);
  rms_finalize<<<32, 256, 0, stream>>>(pss, rsbuf);

  gemm256<1><<<32 * 16, 512, 0, stream>>>(Xb, Wg, (void*)gated, attn, rsbuf, norm_w,
                                          8192, 4096, 4096);
  gemm256<2><<<32 * 16, 512, 0, stream>>>(gated, Wo, d_out, nullptr, nullptr, nullptr,
                                          8192, 4096, 4096);
}

// Round 13
// 1528.226 us; speedup vs baseline: 1.0593x; 1.0593x over previous
//
#include <hip/hip_runtime.h>

typedef unsigned short u16;
typedef __attribute__((ext_vector_type(4))) float f32x4;
typedef __attribute__((ext_vector_type(8))) __bf16 bf16x8;

#define SEQ   4096
#define HID   4096
#define HID3  12288

__device__ __forceinline__ float bf2f(u16 u){
  union { unsigned int i; float f; } v; v.i = ((unsigned int)u) << 16; return v.f;
}
__device__ __forceinline__ u16 f2bf(float f){
  union { float f; unsigned int i; } v; v.f = f;
  unsigned int r = (v.i + 0x7FFFu + ((v.i >> 16) & 1u)) >> 16;
  return (u16)r;
}
__device__ __forceinline__ float slope_of(int h){
  const float factor = 1.0f - 1.0f/(31.0f + 1e-5f) + 1e-5f;
  return exp2f(-0.25f * (float)(h + 1)) * factor;
}
__device__ __forceinline__ bf16x8 ld_bf8(const u16* p){
  return __builtin_bit_cast(bf16x8, *(const uint4*)p);
}
__device__ __forceinline__ void gload_lds16(const u16* g, u16* l){
  __builtin_amdgcn_global_load_lds((const __attribute__((address_space(1))) void*)g,
                                   (__attribute__((address_space(3))) void*)l, 16, 0, 0);
}

// ------- fp32 -> bf16 convert into TILED PRE-SWIZZLED layout (one launch) -------
// Each 16KB chunk = one [256 rows x 32 k] block, content identical to the r4-r11
// LDS slot layout: unit q (16B) holds element (row = 2*(q>>3) + (((q&7)^((q>>3)&7))>>2),
// k8 = ((q&7)^((q>>3)&7))&3).  GEMM staging then becomes a LINEAR 16KB block copy
// (full 128B lines, perfectly coalesced) -- removes the 64B-granular source scatter
// that caused ~2x structural over-fetch (r12 post-mortem: FETCH invariant to order).
// cvt reads: 8 consecutive threads cover two full 128B fp32 source lines (coalesced).
// Chunk ids: Xb 32 tile-rows | Wq 48 | Wg 16 | Wo 16, x 128 kchunks = 14336 chunks.
__global__ __launch_bounds__(256) void cvt4p_kernel(const float* __restrict__ s0,
                                                    const float* __restrict__ s1,
                                                    const float* __restrict__ s2,
                                                    const float* __restrict__ s3,
                                                    u16* __restrict__ dst){
  int c = blockIdx.x;
  int tr = c >> 7, kch = c & 127;
  const float* src; int rowbase;
  if (tr < 32){ src = s0; rowbase = tr * 256; }
  else if (tr < 80){ src = s1; rowbase = (tr - 32) * 256; }
  else if (tr < 96){ src = s2; rowbase = (tr - 80) * 256; }
  else { src = s3; rowbase = (tr - 96) * 256; }
  u16* out = dst + (long)c * 8192;
#pragma unroll
  for (int pass = 0; pass < 4; ++pass){
    int q = pass * 256 + threadIdx.x;
    int dr = q >> 3, up = q & 7;
    int ul = up ^ (dr & 7);
    int row = 2 * dr + (ul >> 2);
    int k8 = ul & 3;
    const float* sp = src + (long)(rowbase + row) * 4096 + kch * 32 + k8 * 8;
    float4 v0 = *(const float4*)sp;
    float4 v1 = *(const float4*)(sp + 4);
    ushort4 o0 = { f2bf(v0.x), f2bf(v0.y), f2bf(v0.z), f2bf(v0.w) };
    ushort4 o1 = { f2bf(v1.x), f2bf(v1.y), f2bf(v1.z), f2bf(v1.w) };
    *(ushort4*)(out + q * 8) = o0;
    *(ushort4*)(out + q * 8 + 4) = o1;
  }
}

// ============ 256x256 tile, BK=64, 5-slot-ring, 1-barrier/period bf16 GEMM ============
// ROUND-9 K-LOOP VERBATIM (verified best: 736us, MfmaUtil 54%, 0 bank conflicts).
// R13: A/B are TILED PRE-SWIZZLED ([tiles][128 kchunks][16KB]); staging source is a
// linear per-chunk block copy.  LDS content, frag offsets, sync, races: unchanged.
// EPI: 0 = silu->bf16 (row-major C) ; 1 = sigmoid(x)*Aux*Rs*Nw -> bf16 written in
// TILED layout (gemm2 consumes it as A) ; 2 = raw->fp32 row-major.
template<int EPI>
__global__ __launch_bounds__(512) void gemm256(
    const u16* __restrict__ A, const u16* __restrict__ B, void* __restrict__ C,
    const u16* __restrict__ Aux, const float* __restrict__ Rs,
    const float* __restrict__ Nw, int M, int N, int K)
{
  __shared__ u16 ring[5][16384];
  const int t = threadIdx.x;
  const int w = t >> 6, l = t & 63, lr = l & 15, lk = l >> 4;
  const int mw = w >> 2, nw = w & 3;
  const int nbn = N >> 8;
  const int nkc = K >> 5;                 // kchunks per tile-row
  int nwg = gridDim.x;
  int bid = blockIdx.x;
  int bswz = (bid & 7) * (nwg >> 3) + (bid >> 3);
  int bm = bswz / nbn, bn = bswz % nbn;
  const int NT = K >> 6;

  // frag read offsets (u16 units within a 16KB chunk) -- r4 layout, unchanged
  int offA[8], offB[4];
#pragma unroll
  for (int fn = 0; fn < 8; ++fn){
    int row = mw * 128 + fn * 16 + lr;
    offA[fn] = (row >> 1) * 64 + (((((row & 1) << 2) + lk) ^ ((row >> 1) & 7)) << 3);
  }
#pragma unroll
  for (int fe = 0; fe < 4; ++fe){
    int row = nw * 64 + fe * 16 + lr;
    offB[fe] = (row >> 1) * 64 + (((((row & 1) << 2) + lk) ^ ((row >> 1) & 7)) << 3);
  }

  // staging: linear block copy of pre-swizzled chunk (bm|bn, kt*2+c)
  auto stageA = [&](int kt, int c, int slot, int i){
    gload_lds16(A + ((long)bm * nkc + kt * 2 + c) * 8192 + i * 4096 + t * 8,
                &ring[slot][i * 4096 + w * 512]);
  };
  auto stageB = [&](int kt, int c, int slot, int i){
    gload_lds16(B + ((long)bn * nkc + kt * 2 + c) * 8192 + i * 4096 + t * 8,
                &ring[slot][8192 + i * 4096 + w * 512]);
  };

  f32x4 acc[8][4] = {};

  // prologue: (0,0)->slot0, (0,1)->slot1, (1,0)->slot2
  stageA(0,0,0,0); stageA(0,0,0,1); stageB(0,0,0,0); stageB(0,0,0,1);
  stageA(0,1,1,0); stageA(0,1,1,1); stageB(0,1,1,0); stageB(0,1,1,1);
  if (1 < NT){ stageA(1,0,2,0); stageA(1,0,2,1); stageB(1,0,2,0); stageB(1,0,2,1); }
  asm volatile("s_waitcnt vmcnt(4)" ::: "memory");
  __builtin_amdgcn_s_barrier();

  int sa = 0;
  for (int p = 0; p < NT; ++p){
    int sb = sa + 1; if (sb >= 5) sb -= 5;
    int sx = sa + 3; if (sx >= 5) sx -= 5;   // chunk (p+1,1)
    int sy = sa + 4; if (sy >= 5) sy -= 5;   // chunk (p+2,0)
    const u16* Aa = &ring[sa][0];
    const u16* Ab = &ring[sb][0];
    const u16* Ba = &ring[sa][8192];
    const u16* Bb = &ring[sb][8192];
    bf16x8 bh0[4], bh1[4], afc0[8], afc1[8];

    // ---- phase 1: chunk sa, fn0-3 ----
#pragma unroll
    for (int fe = 0; fe < 4; ++fe) bh0[fe] = ld_bf8(Ba + offB[fe]);
#pragma unroll
    for (int fn = 0; fn < 4; ++fn) afc0[fn] = ld_bf8(Aa + offA[fn]);
#pragma unroll
    for (int fn = 4; fn < 8; ++fn) afc0[fn] = ld_bf8(Aa + offA[fn]);
    if (p + 1 < NT){ stageA(p+1, 1, sx, 0); stageA(p+1, 1, sx, 1); }
    asm volatile("s_waitcnt lgkmcnt(4)" ::: "memory");
    __builtin_amdgcn_sched_barrier(0);
    __builtin_amdgcn_s_setprio(1);
#pragma unroll
    for (int fn = 0; fn < 4; ++fn)
#pragma unroll
      for (int fe = 0; fe < 4; ++fe)
        acc[fn][fe] = __builtin_amdgcn_mfma_f32_16x16x32_bf16(afc0[fn], bh0[fe], acc[fn][fe], 0, 0, 0);
    __builtin_amdgcn_s_setprio(0);

    // ---- phase 2: chunk sa, fn4-7 ----
#pragma unroll
    for (int fe = 0; fe < 4; ++fe) bh1[fe] = ld_bf8(Bb + offB[fe]);
#pragma unroll
    for (int fn = 0; fn < 4; ++fn) afc1[fn] = ld_bf8(Ab + offA[fn]);
    if (p + 1 < NT){ stageB(p+1, 1, sx, 0); stageB(p+1, 1, sx, 1); }
    asm volatile("s_waitcnt lgkmcnt(8)" ::: "memory");
    __builtin_amdgcn_sched_barrier(0);
    __builtin_amdgcn_s_setprio(1);
#pragma unroll
    for (int fn = 4; fn < 8; ++fn)
#pragma unroll
      for (int fe = 0; fe < 4; ++fe)
        acc[fn][fe] = __builtin_amdgcn_mfma_f32_16x16x32_bf16(afc0[fn], bh0[fe], acc[fn][fe], 0, 0, 0);
    __builtin_amdgcn_s_setprio(0);

    // ---- phase 3: chunk sb, fn0-3 ----
#pragma unroll
    for (int fn = 4; fn < 8; ++fn) afc1[fn] = ld_bf8(Ab + offA[fn]);
    if (p + 2 < NT){ stageA(p+2, 0, sy, 0); stageA(p+2, 0, sy, 1); }
    asm volatile("s_waitcnt lgkmcnt(4)" ::: "memory");
    __builtin_amdgcn_sched_barrier(0);
    __builtin_amdgcn_s_setprio(1);
#pragma unroll
    for (int fn = 0; fn < 4; ++fn)
#pragma unroll
      for (int fe = 0; fe < 4; ++fe)
        acc[fn][fe] = __builtin_amdgcn_mfma_f32_16x16x32_bf16(afc1[fn], bh1[fe], acc[fn][fe], 0, 0, 0);
    __builtin_amdgcn_s_setprio(0);

    // ---- phase 4: chunk sb, fn4-7 ----
    if (p + 2 < NT){ stageB(p+2, 0, sy, 0); stageB(p+2, 0, sy, 1); }
    asm volatile("s_waitcnt lgkmcnt(0)" ::: "memory");
    __builtin_amdgcn_sched_barrier(0);
    __builtin_amdgcn_s_setprio(1);
#pragma unroll
    for (int fn = 4; fn < 8; ++fn)
#pragma unroll
      for (int fe = 0; fe < 4; ++fe)
        acc[fn][fe] = __builtin_amdgcn_mfma_f32_16x16x32_bf16(afc1[fn], bh1[fe], acc[fn][fe], 0, 0, 0);
    __builtin_amdgcn_s_setprio(0);

    // ---- single boundary sync per period ----
    if (p + 2 < NT) asm volatile("s_waitcnt vmcnt(4)" ::: "memory");
    else            asm volatile("s_waitcnt vmcnt(0)" ::: "memory");
    __builtin_amdgcn_s_barrier();
    sa += 2; if (sa >= 5) sa -= 5;
  }

  long crow = (long)bm * 256 + mw * 128 + lk * 4;
  long ccol = (long)bn * 256 + nw * 64 + lr;
#pragma unroll
  for (int fn = 0; fn < 8; ++fn)
#pragma unroll
    for (int fe = 0; fe < 4; ++fe)
#pragma unroll
      for (int reg = 0; reg < 4; ++reg){
        long row = crow + fn * 16 + reg;
        long col = ccol + fe * 16;
        float x = acc[fn][fe][reg];
        if (EPI == 0){
          ((u16*)C)[row * N + col] = f2bf(x / (1.0f + __expf(-x)));
        } else if (EPI == 1){
          float g = 1.0f / (1.0f + __expf(-x));
          float a = bf2f(Aux[row * N + col]);
          // write into TILED pre-swizzled layout (consumed by gemm2 as A)
          int r256 = (int)row & 255;
          int dr2 = r256 >> 1;
          int ul2 = ((r256 & 1) << 2) | (((int)col & 31) >> 3);
          int u2 = ul2 ^ (dr2 & 7);
          long idx = ((long)(row >> 8) * 128 + (col >> 5)) * 8192 + dr2 * 64 + u2 * 8 + (col & 7);
          ((u16*)C)[idx] = f2bf(g * a * Rs[row] * Nw[col]);
        } else {
          ((float*)C)[row * N + col] = x;
        }
      }
}

// ------- attention phase 1 (MFMA): ct[e][d] = sum_n v[n][e] * k[n][d] * kdec[n] -------
__global__ __launch_bounds__(256) void attn_contrib(
    const u16* __restrict__ qkv, float* __restrict__ ct)
{
  __shared__ u16 VT[128 * 258];
  __shared__ u16 KT[128 * 258];
  int wg = blockIdx.x;
  int bh = wg >> 4, blk = wg & 15;
  int b = bh >> 5, h = bh & 31;
  int t = threadIdx.x;
  float slope = slope_of(h);
  const u16* kg = qkv + ((long)(b * SEQ + blk * 256)) * HID3 + h * 384 + 128;
  const u16* vg = kg + 128;
#pragma unroll
  for (int i = 0; i < 16; ++i){
    int chunk = t + i * 256;
    int row = chunk >> 4, c8 = (chunk & 15) << 3;
    float kd = __expf(-slope * (float)(255 - row));
    uint4 kk = *(const uint4*)&kg[(long)row * HID3 + c8];
    uint4 vv = *(const uint4*)&vg[(long)row * HID3 + c8];
    const u16* ks = (const u16*)&kk;
    const u16* vs = (const u16*)&vv;
#pragma unroll
    for (int x = 0; x < 8; ++x){
      KT[(c8 + x) * 258 + row] = f2bf(bf2f(ks[x]) * kd);
      VT[(c8 + x) * 258 + row] = vs[x];
    }
  }
  __syncthreads();
  int w = t >> 6, l = t & 63, lr = l & 15, lk = l >> 4;
  int we = (w >> 1) * 64, wd = (w & 1) * 64;
  f32x4 acc[4][4] = {};
  for (int nc = 0; nc < 8; ++nc){
    bf16x8 va[4], kb[4];
#pragma unroll
    for (int f = 0; f < 4; ++f) va[f] = ld_bf8(&VT[(we + f * 16 + lr) * 258 + nc * 32 + lk * 8]);
#pragma unroll
    for (int f = 0; f < 4; ++f) kb[f] = ld_bf8(&KT[(wd + f * 16 + lr) * 258 + nc * 32 + lk * 8]);
#pragma unroll
    for (int fe = 0; fe < 4; ++fe)
#pragma unroll
      for (int fd = 0; fd < 4; ++fd)
        acc[fe][fd] = __builtin_amdgcn_mfma_f32_16x16x32_bf16(va[fe], kb[fd], acc[fe][fd], 0, 0, 0);
  }
  float* out = ct + (long)wg * 16384;
#pragma unroll
  for (int fe = 0; fe < 4; ++fe)
#pragma unroll
    for (int fd = 0; fd < 4; ++fd)
#pragma unroll
      for (int reg = 0; reg < 4; ++reg){
        int e = we + fe * 16 + lk * 4 + reg;
        int d = wd + fd * 16 + lr;
        out[e * 128 + d] = acc[fe][fd][reg];
      }
}

// ---------------- attention phase 2: decayed prefix scan (d-sliced, 256 blocks) ----
__global__ __launch_bounds__(256) void attn_scan(const float* __restrict__ ct,
                                                 u16* __restrict__ stTb)
{
  int g = blockIdx.x;
  int bh = g >> 2, sl = g & 3;
  int t = threadIdx.x;
  float bdec = __expf(-slope_of(bh & 31) * 256.0f);
  float cur[16];
#pragma unroll
  for (int i = 0; i < 16; ++i) cur[i] = 0.f;
  const float* base = ct + (long)bh * 16 * 16384 + sl * 4096;
  u16* ob = stTb + (long)bh * 16 * 16384 + sl * 4096;
  for (int blkI = 0; blkI < 16; ++blkI){
    const float* p = base + (long)blkI * 16384;
    u16* o = ob + (long)blkI * 16384;
#pragma unroll
    for (int i = 0; i < 16; ++i){
      o[t + i * 256] = f2bf(cur[i]);
      cur[i] = cur[i] * bdec + p[t + i * 256];
    }
  }
}

// ---------------- attention phase 3 (MFMA): intra (causal decay) + inter ----
__global__ __launch_bounds__(512) void attn_mfma(
    const u16* __restrict__ qkv, const u16* __restrict__ stTb, u16* __restrict__ attn)
{
  __shared__ u16 Ks[256 * 130];
  __shared__ u16 VTs[128 * 258];
  __shared__ u16 Ps[4][64 * 34];
  int wg = blockIdx.x;
  int bh = wg >> 4, blk = wg & 15;
  int b = bh >> 5, h = bh & 31;
  int t = threadIdx.x;
  int w = t >> 6, l = t & 63, lr = l & 15, lk = l >> 4;
  int r = w >> 1, c = w & 1;
  float slope = slope_of(h);
  const u16* qg = qkv + ((long)(b * SEQ + blk * 256)) * HID3 + h * 384;
  const u16* kg = qg + 128;
  const u16* vg = qg + 256;

#pragma unroll
  for (int i = 0; i < 8; ++i){
    int chunk = t + i * 512;
    int row = chunk >> 4, c8 = (chunk & 15) << 3;
    *(uint4*)&Ks[row * 130 + c8] = *(const uint4*)&kg[(long)row * HID3 + c8];
    uint4 vv = *(const uint4*)&vg[(long)row * HID3 + c8];
    const u16* vs = (const u16*)&vv;
#pragma unroll
    for (int x = 0; x < 8; ++x) VTs[(c8 + x) * 258 + row] = vs[x];
  }
  bf16x8 qa[4][4];
#pragma unroll
  for (int fn = 0; fn < 4; ++fn)
#pragma unroll
    for (int kc = 0; kc < 4; ++kc)
      qa[fn][kc] = ld_bf8(&qg[(long)(r * 64 + fn * 16 + lr) * HID3 + kc * 32 + lk * 8]);
  f32x4 acc[4][4] = {};
  __syncthreads();

  int mtmax = 2 * r + 1;
  for (int mt = 0; mt < 8; ++mt){
    if (mt <= mtmax){
      f32x4 S[4] = {};
      int mrow = mt * 32 + c * 16 + lr;
      bf16x8 kb[4];
#pragma unroll
      for (int kc = 0; kc < 4; ++kc)
        kb[kc] = ld_bf8(&Ks[mrow * 130 + kc * 32 + lk * 8]);
#pragma unroll
      for (int fn = 0; fn < 4; ++fn)
#pragma unroll
        for (int kc = 0; kc < 4; ++kc)
          S[fn] = __builtin_amdgcn_mfma_f32_16x16x32_bf16(qa[fn][kc], kb[kc], S[fn], 0, 0, 0);
      int m = mt * 32 + c * 16 + lr;
#pragma unroll
      for (int fn = 0; fn < 4; ++fn)
#pragma unroll
        for (int reg = 0; reg < 4; ++reg){
          int n = r * 64 + fn * 16 + lk * 4 + reg;
          float dv = (n >= m) ? __expf(-slope * (float)(n - m)) : 0.f;
          Ps[r][(fn * 16 + lk * 4 + reg) * 34 + c * 16 + lr] = f2bf(S[fn][reg] * dv);
        }
    }
    __syncthreads();
    if (mt <= mtmax){
      bf16x8 pa[4], vb[4];
#pragma unroll
      for (int fn = 0; fn < 4; ++fn)
        pa[fn] = ld_bf8(&Ps[r][(fn * 16 + lr) * 34 + lk * 8]);
#pragma unroll
      for (int fe = 0; fe < 4; ++fe)
        vb[fe] = ld_bf8(&VTs[(c * 64 + fe * 16 + lr) * 258 + mt * 32 + lk * 8]);
#pragma unroll
      for (int fn = 0; fn < 4; ++fn)
#pragma unroll
        for (int fe = 0; fe < 4; ++fe)
          acc[fn][fe] = __builtin_amdgcn_mfma_f32_16x16x32_bf16(pa[fn], vb[fe], acc[fn][fe], 0, 0, 0);
    }
    __syncthreads();
  }

#pragma unroll
  for (int fn = 0; fn < 4; ++fn){
    int n = r * 64 + fn * 16 + lr;
    float qd = __expf(-slope * (float)(n + 1));
#pragma unroll
    for (int kc = 0; kc < 4; ++kc){
      union { bf16x8 v; u16 u[8]; } uu; uu.v = qa[fn][kc];
#pragma unroll
      for (int x = 0; x < 8; ++x) uu.u[x] = f2bf(bf2f(uu.u[x]) * qd);
      qa[fn][kc] = uu.v;
    }
  }
  const u16* sg = stTb + (long)(bh * 16 + blk) * 16384;
#pragma unroll
  for (int kc = 0; kc < 4; ++kc){
    bf16x8 sb2[4];
#pragma unroll
    for (int fe = 0; fe < 4; ++fe)
      sb2[fe] = ld_bf8(&sg[(c * 64 + fe * 16 + lr) * 128 + kc * 32 + lk * 8]);
#pragma unroll
    for (int fn = 0; fn < 4; ++fn)
#pragma unroll
      for (int fe = 0; fe < 4; ++fe)
        acc[fn][fe] = __builtin_amdgcn_mfma_f32_16x16x32_bf16(qa[fn][kc], sb2[fe], acc[fn][fe], 0, 0, 0);
  }

  u16* arow = attn + ((long)(b * SEQ + blk * 256)) * HID + h * 128;
#pragma unroll
  for (int fn = 0; fn < 4; ++fn)
#pragma unroll
    for (int fe = 0; fe < 4; ++fe)
#pragma unroll
      for (int reg = 0; reg < 4; ++reg){
        int n = r * 64 + fn * 16 + lk * 4 + reg;
        int col = c * 64 + fe * 16 + lr;
        arow[(long)n * HID + col] = f2bf(acc[fn][fe][reg]);
      }
}

// ---------------- RMSNorm stats only: rs[row] = rsqrt(mean(attn_row^2)+eps) ----------
__global__ __launch_bounds__(256) void rmsnorm_stats(const u16* __restrict__ attn,
                                                     float* __restrict__ rs)
{
  __shared__ float wsum[4];
  int row = blockIdx.x, t = threadIdx.x;
  const u16* p = attn + (long)row * HID;
  uint4 v0 = *(const uint4*)&p[t * 8];
  uint4 v1 = *(const uint4*)&p[t * 8 + 2048];
  const u16* a0 = (const u16*)&v0;
  const u16* a1 = (const u16*)&v1;
  float ss = 0.f;
#pragma unroll
  for (int x = 0; x < 8; ++x){
    float f0 = bf2f(a0[x]), f1 = bf2f(a1[x]);
    ss += f0 * f0 + f1 * f1;
  }
#pragma unroll
  for (int off = 32; off > 0; off >>= 1) ss += __shfl_down(ss, off);
  if ((t & 63) == 0) wsum[t >> 6] = ss;
  __syncthreads();
  if (t == 0)
    rs[row] = rsqrtf((wsum[0] + wsum[1] + wsum[2] + wsum[3]) * (1.0f / 4096.0f) + 1e-5f);
}

// ---------------- launch ----------------
extern "C" void kernel_launch(void* const* d_in, const int* in_sizes, int n_in,
                              void* d_out, int out_size, void* d_ws, size_t ws_size,
                              hipStream_t stream)
{
  const float* hidden = (const float*)d_in[0];
  const float* qkv_w  = (const float*)d_in[1];
  const float* out_w  = (const float*)d_in[2];
  const float* gate_w = (const float*)d_in[3];
  const float* norm_w = (const float*)d_in[4];
  char* ws = (char*)d_ws;
  const long SZ_X  = 67108864L;    // 8192*4096 bf16 (tiled)
  const long SZ_WQ = 100663296L;   // 12288*4096 bf16 (tiled)
  const long SZ_WG = 33554432L;
  const long SZ_WO = 33554432L;
  const long SZ_QA = 201326592L;   // 8192*12288 bf16 (row-major)
  const long SZ_AT = 67108864L;    // 8192*4096 bf16 (row-major)
  u16* Xb   = (u16*)(ws);
  u16* Wq   = (u16*)(ws + SZ_X);
  u16* Wg   = (u16*)(ws + SZ_X + SZ_WQ);
  u16* Wo   = (u16*)(ws + SZ_X + SZ_WQ + SZ_WG);
  u16* qact = (u16*)(ws + SZ_X + SZ_WQ + SZ_WG + SZ_WO);
  u16* attn = (u16*)(ws + SZ_X + SZ_WQ + SZ_WG + SZ_WO + SZ_QA);
  float* st   = (float*)Wq;        // 67MB, overlays Wq (dead after gemm<0>)
  u16*   stTb = (u16*)(ws + SZ_X + 67108864L);
  float* rsbuf = (float*)Wq;       // 32KB, overlays st (dead after attn_scan)
  u16* gated = qact;               // overlays qkv activations (dead after attention)
  if (ws_size < (size_t)(SZ_X + SZ_WQ + SZ_WG + SZ_WO + SZ_QA + SZ_AT)) return;

  // tiled pre-swizzled conversion: Xb | Wq | Wg | Wo  (14336 chunks x 16KB)
  cvt4p_kernel<<<14336, 256, 0, stream>>>(hidden, qkv_w, gate_w, out_w, Xb);

  gemm256<0><<<32 * 48, 512, 0, stream>>>(Xb, Wq, (void*)qact, nullptr, nullptr, nullptr,
                                          8192, 12288, 4096);

  attn_contrib<<<1024, 256, 0, stream>>>(qact, st);
  attn_scan<<<256, 256, 0, stream>>>(st, stTb);
  attn_mfma<<<1024, 512, 0, stream>>>(qact, stTb, attn);
  rmsnorm_stats<<<8192, 256, 0, stream>>>(attn, rsbuf);

  gemm256<1><<<32 * 16, 512, 0, stream>>>(Xb, Wg, (void*)gated, attn, rsbuf, norm_w,
                                          8192, 4096, 4096);
  gemm256<2><<<32 * 16, 512, 0, stream>>>(gated, Wo, d_out, nullptr, nullptr, nullptr,
                                          8192, 4096, 4096);
}